// Round 5
// baseline (173.050 us; speedup 1.0000x reference)
//
#include <hip/hip_runtime.h>

// VDP dropout:
//   keep      = (u >= 0.1f)
//   mu_out    = mu_in    * keep / 0.9
//   Sigma_out = Sigma_in * keep / 768     (D = last-dim size)
//
// N = 64*197*768 = 9,682,944 fp32. Memory-bound, ~194 MB logical traffic
// (135 MB HBM after L3 absorption of ~half the reads).
// R4: PERSISTENT grid-stride kernel — 2048 blocks (8 blocks/CU at 8 VGPR =
// full 32-wave occupancy), each thread loops ~4.6 float4 iterations with
// grid stride (every iteration fully coalesced). Removes ~7400 workgroup
// launch/teardowns vs R0's 9456-block one-shot grid. nt stores retained.

#define DROP_PROP 0.1f

typedef float vfloat4 __attribute__((ext_vector_type(4)));

__global__ __launch_bounds__(256) void vdp_dropout_kernel(
    const vfloat4* __restrict__ mu_in,
    const vfloat4* __restrict__ sigma_in,
    const vfloat4* __restrict__ u,
    vfloat4* __restrict__ mu_out,
    vfloat4* __restrict__ sigma_out,
    int n4)
{
    const float inv_keep = 1.0f / (1.0f - DROP_PROP);   // 1/0.9
    const float inv_d    = 1.0f / 768.0f;

    const int stride = gridDim.x * blockDim.x;          // 524,288
    for (int i = blockIdx.x * blockDim.x + threadIdx.x; i < n4; i += stride) {
        vfloat4 uu = u[i];
        vfloat4 m  = mu_in[i];
        vfloat4 s  = sigma_in[i];

        vfloat4 mo, so;
        mo.x = (uu.x >= DROP_PROP) ? m.x * inv_keep : 0.0f;
        mo.y = (uu.y >= DROP_PROP) ? m.y * inv_keep : 0.0f;
        mo.z = (uu.z >= DROP_PROP) ? m.z * inv_keep : 0.0f;
        mo.w = (uu.w >= DROP_PROP) ? m.w * inv_keep : 0.0f;

        so.x = (uu.x >= DROP_PROP) ? s.x * inv_d : 0.0f;
        so.y = (uu.y >= DROP_PROP) ? s.y * inv_d : 0.0f;
        so.z = (uu.z >= DROP_PROP) ? s.z * inv_d : 0.0f;
        so.w = (uu.w >= DROP_PROP) ? s.w * inv_d : 0.0f;

        __builtin_nontemporal_store(mo, &mu_out[i]);
        __builtin_nontemporal_store(so, &sigma_out[i]);
    }
}

extern "C" void kernel_launch(void* const* d_in, const int* in_sizes, int n_in,
                              void* d_out, int out_size, void* d_ws, size_t ws_size,
                              hipStream_t stream)
{
    const float* mu_in    = (const float*)d_in[0];
    const float* sigma_in = (const float*)d_in[1];
    const float* u        = (const float*)d_in[2];

    const int n = in_sizes[0];          // 9,682,944
    float* mu_out    = (float*)d_out;           // first n elements
    float* sigma_out = (float*)d_out + n;       // next n elements

    const int n4 = n / 4;               // 2,420,736
    const int block = 256;
    const int grid = 2048;              // 8 blocks/CU * 256 CUs (persistent)

    vdp_dropout_kernel<<<grid, block, 0, stream>>>(
        (const vfloat4*)mu_in, (const vfloat4*)sigma_in, (const vfloat4*)u,
        (vfloat4*)mu_out, (vfloat4*)sigma_out, n4);
}